// Round 2
// baseline (175.098 us; speedup 1.0000x reference)
//
#include <hip/hip_runtime.h>
#include <math.h>

#define NCLS 80
#define BINS 17
#define REGMAX 16
#define NG 32
#define NB 16
#define KTOP 10
#define RAD 2.5f

// ---------- workspace layout (bytes) ----------
// [0,   8)    : float acc[2]   (box_sum, cls_sum)
// [32,  224)  : float npos[3][NB]
// [224, 416)  : float dfln[3][NB]
// [416, 608)  : int   anyp[3][NB]
// [608, 62048): int   fb[3][NB][NG][KTOP]
#define WS_ACC   0
#define WS_NPOS  32
#define WS_DFLN  224
#define WS_ANYP  416
#define WS_FB    608
#define WS_TOTAL (608 + 3*NB*NG*KTOP*4)

// focal_bce with t=0: ce*0.75*p^2   (single exp + single log)
__device__ __forceinline__ float focal0(float x) {
    float e   = __expf(-fabsf(x));
    float inv = 1.0f / (1.0f + e);
    float p   = (x >= 0.0f) ? inv : e * inv;          // sigmoid(x)
    float ce  = fmaxf(x, 0.0f) + __logf(1.0f + e);
    return ce * 0.75f * p * p;
}

__device__ __forceinline__ float focal_t(float x, float t) {
    float e   = __expf(-fabsf(x));
    float inv = 1.0f / (1.0f + e);
    float p   = (x >= 0.0f) ? inv : e * inv;
    float ce  = fmaxf(x, 0.0f) - x * t + __logf(1.0f + e);
    float pt  = p * t + (1.0f - p) * (1.0f - t);
    float at  = 0.25f * t + 0.75f * (1.0f - t);
    float om  = 1.0f - pt;
    return ce * at * om * om;
}

// ---------------- pass 1: any_pos[lvl][b], all levels fused ----------------
__global__ void k_anypos_f(const float* __restrict__ gtb, int* __restrict__ anyp) {
    int bx = blockIdx.x, b = blockIdx.y;
    int lvl, p0, W; float inv_s;
    if (bx < 25)      { lvl = 0; p0 = bx * 256;        W = 80; inv_s = 0.125f;   }
    else if (bx < 32) { lvl = 1; p0 = (bx - 25) * 256; W = 40; inv_s = 0.0625f;  }
    else              { lvl = 2; p0 = (bx - 32) * 256; W = 20; inv_s = 0.03125f; }
    int HW = W * W;
    int p  = p0 + threadIdx.x;
    bool any = false;
    if (p < HW) {
        float cx = (float)(p % W) + 0.5f;
        float cy = (float)(p / W) + 0.5f;
        for (int g = 0; g < NG; ++g) {
            const float* bb = gtb + (b * NG + g) * 4;
            float x1 = bb[0] * inv_s, y1 = bb[1] * inv_s;
            float x2 = bb[2] * inv_s, y2 = bb[3] * inv_s;
            float gcx = (x1 + x2) * 0.5f, gcy = (y1 + y2) * 0.5f;
            bool m = (cx - x1 > 0.0f) && (cy - y1 > 0.0f) &&
                     (x2 - cx > 0.0f) && (y2 - cy > 0.0f) &&
                     (cx >= gcx - RAD) && (cx <= gcx + RAD) &&
                     (cy >= gcy - RAD) && (cy <= gcy + RAD);
            any = any || m;
        }
    }
    if (__any(any) && (threadIdx.x & 63) == 0) atomicOr(anyp + lvl * NB + b, 1);
}

// ---------------- pass 2: top-10 fallback (rarely taken), levels fused ------
__global__ void k_fallback_f(const float* __restrict__ gtb, const int* __restrict__ anyp,
                             int* __restrict__ fb) {
    int b = blockIdx.x, lvl = blockIdx.y;
    int W = (lvl == 0) ? 80 : (lvl == 1 ? 40 : 20);
    float inv_s = (lvl == 0) ? 0.125f : (lvl == 1 ? 0.0625f : 0.03125f);
    if (anyp[lvl * NB + b]) return;
    int g = threadIdx.x;
    if (g >= NG) return;
    const float* bb = gtb + (b * NG + g) * 4;
    float gcx = (bb[0] * inv_s + bb[2] * inv_s) * 0.5f;
    float gcy = (bb[1] * inv_s + bb[3] * inv_s) * 0.5f;
    float bd[KTOP];
    int   bi[KTOP];
    for (int t = 0; t < KTOP; ++t) { bd[t] = 3.0e38f; bi[t] = 0; }
    int HW = W * W;
    for (int p = 0; p < HW; ++p) {
        float cx = (float)(p % W) + 0.5f;
        float cy = (float)(p / W) + 0.5f;
        float dx = cx - gcx, dy = cy - gcy;
        float d = dx * dx + dy * dy;
        if (d < bd[KTOP - 1]) {
            int t = KTOP - 1;
            while (t > 0 && d < bd[t - 1]) { bd[t] = bd[t - 1]; bi[t] = bi[t - 1]; --t; }
            bd[t] = d; bi[t] = p;
        }
    }
    int* o = fb + ((lvl * NB + b) * NG + g) * KTOP;
    for (int t = 0; t < KTOP; ++t) o[t] = bi[t];
}

// ---------------- pass 3: main loss — 8 lanes per grid point, levels fused --
__global__ __launch_bounds__(256) void k_main_f(
    const float* __restrict__ reg0, const float* __restrict__ cls0,
    const float* __restrict__ reg1, const float* __restrict__ cls1,
    const float* __restrict__ reg2, const float* __restrict__ cls2,
    const float* __restrict__ gtb,  const int* __restrict__ lab,
    const int* __restrict__ anyp,   const int* __restrict__ fb,
    float* __restrict__ acc, float* __restrict__ npos, float* __restrict__ dfln)
{
    int bx = blockIdx.x;
    int b  = blockIdx.y;
    int lvl, p0, W; const float *regp, *clsp; float inv_s;
    if (bx < 200)      { lvl = 0; p0 = bx * 32;         W = 80; regp = reg0; clsp = cls0; inv_s = 0.125f;   }
    else if (bx < 250) { lvl = 1; p0 = (bx - 200) * 32; W = 40; regp = reg1; clsp = cls1; inv_s = 0.0625f;  }
    else               { lvl = 2; p0 = (bx - 250) * 32; W = 20; regp = reg2; clsp = cls2; inv_s = 0.03125f; }
    int HW = W * W;

    int lane = threadIdx.x & 63;
    int sub  = threadIdx.x & 7;           // lane within the 8-lane point group
    int p    = p0 + (threadIdx.x >> 3);
    bool valid = p < HW;
    int pc = valid ? p : 0;
    float cx = (float)(pc % W) + 0.5f;
    float cy = (float)(pc / W) + 0.5f;

    int base_r = (b * 4 * BINS) * HW + pc;
    int base_c = (b * NCLS) * HW + pc;

    // lanes 0-3 of each group: softmax stats for distribution k = sub
    float dv_own = 0.0f, lz_own = 0.0f;
    if (sub < 4) {
        float x[BINS];
#pragma unroll
        for (int t = 0; t < BINS; ++t) x[t] = regp[base_r + (sub * BINS + t) * HW];
        float m = x[0];
#pragma unroll
        for (int t = 1; t < BINS; ++t) m = fmaxf(m, x[t]);
        float s = 0.0f, e = 0.0f;
#pragma unroll
        for (int t = 0; t < BINS; ++t) {
            float ee = __expf(x[t] - m);
            s += ee; e += ee * (float)t;
        }
        dv_own = e / s;
        lz_own = __logf(s) + m;
    }
    // broadcast dv/lz to all 8 lanes of the group
    int gb = lane & ~7;
    float dv[4], lz[4];
#pragma unroll
    for (int k = 0; k < 4; ++k) {
        dv[k] = __shfl(dv_own, gb + k);
        lz[k] = __shfl(lz_own, gb + k);
    }
    float px1 = cx - dv[0], py1 = cy - dv[1];
    float px2 = cx + dv[2], py2 = cy + dv[3];
    float pa = (px2 - px1) * (py2 - py1);

    // focal0 sum over classes, split 7/7/7/7/13/13/13/13 across the group
    int coff = (sub < 4) ? sub * 7 : 28 + (sub - 4) * 13;
    int ccnt = (sub < 4) ? 7 : 13;
    float fzs = 0.0f;
    for (int t = 0; t < 13; ++t) {
        if (t < ccnt) fzs += focal0(clsp[base_c + (coff + t) * HW]);
    }
    fzs += __shfl_xor(fzs, 1);
    fzs += __shfl_xor(fzs, 2);
    fzs += __shfl_xor(fzs, 4);

    bool anyb = anyp[lvl * NB + b] != 0;
    float bxa = 0.0f, cla = 0.0f, dfa = 0.0f, np = 0.0f;
    int posi = 0;

    // each lane handles g = sub, sub+8, sub+16, sub+24
#pragma unroll
    for (int t = 0; t < 4; ++t) {
        int g = sub + 8 * t;
        const float* bb = gtb + (b * NG + g) * 4;
        float x1 = bb[0] * inv_s, y1 = bb[1] * inv_s;
        float x2 = bb[2] * inv_s, y2 = bb[3] * inv_s;
        float dl = cx - x1, dt = cy - y1, dr = x2 - cx, db = y2 - cy;
        bool msk;
        if (anyb) {
            float gcx = (x1 + x2) * 0.5f, gcy = (y1 + y2) * 0.5f;
            msk = (dl > 0.0f) && (dt > 0.0f) && (dr > 0.0f) && (db > 0.0f) &&
                  (cx >= gcx - RAD) && (cx <= gcx + RAD) &&
                  (cy >= gcy - RAD) && (cy <= gcy + RAD);
        } else {
            msk = false;
            const int* fbp = fb + ((lvl * NB + b) * NG + g) * KTOP;
#pragma unroll
            for (int q = 0; q < KTOP; ++q) msk = msk || (fbp[q] == pc);
        }
        msk = msk && valid;
        if (msk) {
            posi = 1;
            np += 1.0f;
            float ix1 = fmaxf(px1, x1), iy1 = fmaxf(py1, y1);
            float ix2 = fminf(px2, x2), iy2 = fminf(py2, y2);
            float iw = fmaxf(ix2 - ix1, 0.0f), ih = fmaxf(iy2 - iy1, 0.0f);
            float inter = iw * ih;
            float ga = (x2 - x1) * (y2 - y1);
            float iou = inter / (pa + ga - inter + 1e-6f);
            bxa += 1.0f - iou;
            float ltrb[4] = { dl, dt, dr, db };
#pragma unroll
            for (int k = 0; k < 4; ++k) {
                float tt = fminf(fmaxf(ltrb[k], 0.0f), 15.9999f);
                float lf = floorf(tt);
                int   lb = (int)lf;
                int   rb = lb + 1 > REGMAX ? REGMAX : lb + 1;
                float wl = (float)rb - tt, wr = tt - lf;
                float xl = regp[base_r + (k * BINS + lb) * HW];
                float xr = regp[base_r + (k * BINS + rb) * HW];
                dfa -= (xl - lz[k]) * wl + (xr - lz[k]) * wr;
            }
            int   c   = lab[b * NG + g];
            float xat = clsp[base_c + c * HW];
            cla += fzs - focal0(xat) + focal_t(xat, iou);
        }
    }
    // group-wide "any positive" OR
    int pg = posi;
    pg |= __shfl_xor(pg, 1);
    pg |= __shfl_xor(pg, 2);
    pg |= __shfl_xor(pg, 4);
    if (valid && !pg && sub == 0) cla += fzs;   // cls_neg once per point

    // wave + block reduction
    float v0 = bxa, v1 = cla, v2 = dfa, v3 = np;
    for (int off = 32; off > 0; off >>= 1) {
        v0 += __shfl_down(v0, off);
        v1 += __shfl_down(v1, off);
        v2 += __shfl_down(v2, off);
        v3 += __shfl_down(v3, off);
    }
    __shared__ float red[4][4];
    int wid = threadIdx.x >> 6;
    if ((threadIdx.x & 63) == 0) {
        red[wid][0] = v0; red[wid][1] = v1; red[wid][2] = v2; red[wid][3] = v3;
    }
    __syncthreads();
    if (threadIdx.x == 0) {
        float s0 = 0, s1 = 0, s2 = 0, s3 = 0;
        for (int w = 0; w < 4; ++w) {
            s0 += red[w][0]; s1 += red[w][1]; s2 += red[w][2]; s3 += red[w][3];
        }
        atomicAdd(&acc[0], s0);
        atomicAdd(&acc[1], s1);
        atomicAdd(&dfln[lvl * NB + b], s2);
        atomicAdd(&npos[lvl * NB + b], s3);
    }
}

// ---------------- pass 4: combine ----------------
__global__ void k_final(const float* __restrict__ acc, const float* __restrict__ npos,
                        const float* __restrict__ dfln, float* __restrict__ out) {
    float tb = acc[0], tc = acc[1], td = 0.0f;
    for (int i = 0; i < 3 * NB; ++i) {
        float n = npos[i];
        if (n > 0.0f) td += dfln[i] / (n * 4.0f);
    }
    out[0] = 7.5f * tb + 1.0f * tc + 1.5f * td;
    out[1] = tb;
    out[2] = tc;
    out[3] = td;
}

extern "C" void kernel_launch(void* const* d_in, const int* in_sizes, int n_in,
                              void* d_out, int out_size, void* d_ws, size_t ws_size,
                              hipStream_t stream) {
    const float* reg0 = (const float*)d_in[0];
    const float* cls0 = (const float*)d_in[1];
    const float* reg1 = (const float*)d_in[2];
    const float* cls1 = (const float*)d_in[3];
    const float* reg2 = (const float*)d_in[4];
    const float* cls2 = (const float*)d_in[5];
    const float* gtb  = (const float*)d_in[6];
    const int*   lab  = (const int*)d_in[7];
    float* out = (float*)d_out;

    char*  ws   = (char*)d_ws;
    float* acc  = (float*)(ws + WS_ACC);
    float* npos = (float*)(ws + WS_NPOS);
    float* dfln = (float*)(ws + WS_DFLN);
    int*   anyp = (int*)(ws + WS_ANYP);
    int*   fb   = (int*)(ws + WS_FB);

    hipMemsetAsync(d_ws, 0, WS_TOTAL, stream);

    // pass 1: any_pos for all levels (L0:25 blocks, L1:7, L2:2 per batch)
    k_anypos_f<<<dim3(34, NB), 256, 0, stream>>>(gtb, anyp);
    // pass 2: fallback top-10 (almost never taken)
    k_fallback_f<<<dim3(NB, 3), 64, 0, stream>>>(gtb, anyp, fb);
    // pass 3: fused main loss. 8 lanes per point, 32 points per 256-thr block.
    // L0: 200 blocks, L1: 50, L2: 13  ->  263 x 16
    k_main_f<<<dim3(263, NB), 256, 0, stream>>>(reg0, cls0, reg1, cls1, reg2, cls2,
                                                gtb, lab, anyp, fb,
                                                acc, npos, dfln);
    k_final<<<1, 1, 0, stream>>>(acc, npos, dfln, out);
}

// Round 3
// 112.840 us; speedup vs baseline: 1.5517x; 1.5517x over previous
//
#include <hip/hip_runtime.h>
#include <math.h>

#define NCLS 80
#define BINS 17
#define REGMAX 16
#define NG 32
#define NB 16
#define KTOP 10
#define RAD 2.5f

// ---------- workspace layout (bytes) ----------
#define WS_ACC   0
#define WS_NPOS  32
#define WS_DFLN  224
#define WS_ANYP  416
#define WS_FB    608
#define WS_TOTAL (608 + 3*NB*NG*KTOP*4)

// focal_bce with t=0: ce*0.75*p^2   (single exp + single log)
__device__ __forceinline__ float focal0(float x) {
    float e   = __expf(-fabsf(x));
    float inv = 1.0f / (1.0f + e);
    float p   = (x >= 0.0f) ? inv : e * inv;          // sigmoid(x)
    float ce  = fmaxf(x, 0.0f) + __logf(1.0f + e);
    return ce * 0.75f * p * p;
}

__device__ __forceinline__ float focal_t(float x, float t) {
    float e   = __expf(-fabsf(x));
    float inv = 1.0f / (1.0f + e);
    float p   = (x >= 0.0f) ? inv : e * inv;
    float ce  = fmaxf(x, 0.0f) - x * t + __logf(1.0f + e);
    float pt  = p * t + (1.0f - p) * (1.0f - t);
    float at  = 0.25f * t + 0.75f * (1.0f - t);
    float om  = 1.0f - pt;
    return ce * at * om * om;
}

// ---------------- pass 1: any_pos[lvl][b], all levels fused ----------------
__global__ void k_anypos_f(const float* __restrict__ gtb, int* __restrict__ anyp) {
    int bx = blockIdx.x, b = blockIdx.y;
    int lvl, p0, W; float inv_s;
    if (bx < 25)      { lvl = 0; p0 = bx * 256;        W = 80; inv_s = 0.125f;   }
    else if (bx < 32) { lvl = 1; p0 = (bx - 25) * 256; W = 40; inv_s = 0.0625f;  }
    else              { lvl = 2; p0 = (bx - 32) * 256; W = 20; inv_s = 0.03125f; }
    int HW = W * W;
    int p  = p0 + threadIdx.x;
    bool any = false;
    if (p < HW) {
        float cx = (float)(p % W) + 0.5f;
        float cy = (float)(p / W) + 0.5f;
        for (int g = 0; g < NG; ++g) {
            const float* bb = gtb + (b * NG + g) * 4;
            float x1 = bb[0] * inv_s, y1 = bb[1] * inv_s;
            float x2 = bb[2] * inv_s, y2 = bb[3] * inv_s;
            float gcx = (x1 + x2) * 0.5f, gcy = (y1 + y2) * 0.5f;
            bool m = (cx - x1 > 0.0f) && (cy - y1 > 0.0f) &&
                     (x2 - cx > 0.0f) && (y2 - cy > 0.0f) &&
                     (cx >= gcx - RAD) && (cx <= gcx + RAD) &&
                     (cy >= gcy - RAD) && (cy <= gcy + RAD);
            any = any || m;
        }
    }
    if (__any(any) && (threadIdx.x & 63) == 0) atomicOr(anyp + lvl * NB + b, 1);
}

// ---------------- pass 2: top-10 fallback (rarely taken), levels fused ------
__global__ void k_fallback_f(const float* __restrict__ gtb, const int* __restrict__ anyp,
                             int* __restrict__ fb) {
    int b = blockIdx.x, lvl = blockIdx.y;
    int W = (lvl == 0) ? 80 : (lvl == 1 ? 40 : 20);
    float inv_s = (lvl == 0) ? 0.125f : (lvl == 1 ? 0.0625f : 0.03125f);
    if (anyp[lvl * NB + b]) return;
    int g = threadIdx.x;
    if (g >= NG) return;
    const float* bb = gtb + (b * NG + g) * 4;
    float gcx = (bb[0] * inv_s + bb[2] * inv_s) * 0.5f;
    float gcy = (bb[1] * inv_s + bb[3] * inv_s) * 0.5f;
    float bd[KTOP];
    int   bi[KTOP];
    for (int t = 0; t < KTOP; ++t) { bd[t] = 3.0e38f; bi[t] = 0; }
    int HW = W * W;
    for (int p = 0; p < HW; ++p) {
        float cx = (float)(p % W) + 0.5f;
        float cy = (float)(p / W) + 0.5f;
        float dx = cx - gcx, dy = cy - gcy;
        float d = dx * dx + dy * dy;
        if (d < bd[KTOP - 1]) {
            int t = KTOP - 1;
            while (t > 0 && d < bd[t - 1]) { bd[t] = bd[t - 1]; bi[t] = bi[t - 1]; --t; }
            bd[t] = d; bi[t] = p;
        }
    }
    int* o = fb + ((lvl * NB + b) * NG + g) * KTOP;
    for (int t = 0; t < KTOP; ++t) o[t] = bi[t];
}

// -------- pass 3: main loss. Block = 64 points x 4 wave-slices. --------
// Slice s (one wave): softmax dist k=s, classes [s*20, s*20+20), g in [s*8, s*8+8).
// Waves stay coalesced: lane = consecutive point, channel-strided loads.
__global__ __launch_bounds__(256) void k_main_f(
    const float* __restrict__ reg0, const float* __restrict__ cls0,
    const float* __restrict__ reg1, const float* __restrict__ cls1,
    const float* __restrict__ reg2, const float* __restrict__ cls2,
    const float* __restrict__ gtb,  const int* __restrict__ lab,
    const int* __restrict__ anyp,   const int* __restrict__ fb,
    float* __restrict__ acc, float* __restrict__ npos, float* __restrict__ dfln)
{
    int bx = blockIdx.x;
    int b  = blockIdx.y;
    int lvl, pb, W; const float *regp, *clsp; float inv_s;
    if (bx < 100)      { lvl = 0; pb = bx;       W = 80; regp = reg0; clsp = cls0; inv_s = 0.125f;   }
    else if (bx < 125) { lvl = 1; pb = bx - 100; W = 40; regp = reg1; clsp = cls1; inv_s = 0.0625f;  }
    else               { lvl = 2; pb = bx - 125; W = 20; regp = reg2; clsp = cls2; inv_s = 0.03125f; }
    int HW = W * W;

    int x = threadIdx.x & 63;     // point within block (lane)
    int s = threadIdx.x >> 6;     // slice (wave id)
    int p = pb * 64 + x;
    bool valid = p < HW;
    int pc = valid ? p : 0;
    float cx = (float)(pc % W) + 0.5f;
    float cy = (float)(pc / W) + 0.5f;

    int base_r = (b * 4 * BINS) * HW + pc;
    int base_c = (b * NCLS) * HW + pc;

    __shared__ float s_dv[4][64];
    __shared__ float s_lz[4][64];
    __shared__ float s_fz[4][64];
    __shared__ int   s_ps[4][64];

    // --- phase 1: softmax stats for distribution k = s ---
    {
        float xv[BINS];
#pragma unroll
        for (int t = 0; t < BINS; ++t) xv[t] = regp[base_r + (s * BINS + t) * HW];
        float m = xv[0];
#pragma unroll
        for (int t = 1; t < BINS; ++t) m = fmaxf(m, xv[t]);
        float sum = 0.0f, ex = 0.0f;
#pragma unroll
        for (int t = 0; t < BINS; ++t) {
            float ee = __expf(xv[t] - m);
            sum += ee; ex += ee * (float)t;
        }
        s_dv[s][x] = ex / sum;
        s_lz[s][x] = __logf(sum) + m;
    }
    // --- phase 1b: focal0 over 20 classes ---
    {
        float fzp = 0.0f;
#pragma unroll 4
        for (int t = 0; t < 20; ++t)
            fzp += focal0(clsp[base_c + (s * 20 + t) * HW]);
        s_fz[s][x] = fzp;
    }
    __syncthreads();

    float dv[4], lz[4];
#pragma unroll
    for (int k = 0; k < 4; ++k) { dv[k] = s_dv[k][x]; lz[k] = s_lz[k][x]; }
    float fzs = s_fz[0][x] + s_fz[1][x] + s_fz[2][x] + s_fz[3][x];

    float px1 = cx - dv[0], py1 = cy - dv[1];
    float px2 = cx + dv[2], py2 = cy + dv[3];
    float pa = (px2 - px1) * (py2 - py1);

    bool anyb = anyp[lvl * NB + b] != 0;
    float bxa = 0.0f, cla = 0.0f, dfa = 0.0f, np = 0.0f;
    int posi = 0;

    // --- phase 2: g-loop, this slice handles g = s*8 .. s*8+7 ---
#pragma unroll
    for (int t = 0; t < 8; ++t) {
        int g = s * 8 + t;
        const float* bb = gtb + (b * NG + g) * 4;
        float x1 = bb[0] * inv_s, y1 = bb[1] * inv_s;
        float x2 = bb[2] * inv_s, y2 = bb[3] * inv_s;
        float dl = cx - x1, dt = cy - y1, dr = x2 - cx, db = y2 - cy;
        bool msk;
        if (anyb) {
            float gcx = (x1 + x2) * 0.5f, gcy = (y1 + y2) * 0.5f;
            msk = (dl > 0.0f) && (dt > 0.0f) && (dr > 0.0f) && (db > 0.0f) &&
                  (cx >= gcx - RAD) && (cx <= gcx + RAD) &&
                  (cy >= gcy - RAD) && (cy <= gcy + RAD);
        } else {
            msk = false;
            const int* fbp = fb + ((lvl * NB + b) * NG + g) * KTOP;
#pragma unroll
            for (int q = 0; q < KTOP; ++q) msk = msk || (fbp[q] == pc);
        }
        msk = msk && valid;
        if (msk) {
            posi = 1;
            np += 1.0f;
            float ix1 = fmaxf(px1, x1), iy1 = fmaxf(py1, y1);
            float ix2 = fminf(px2, x2), iy2 = fminf(py2, y2);
            float iw = fmaxf(ix2 - ix1, 0.0f), ih = fmaxf(iy2 - iy1, 0.0f);
            float inter = iw * ih;
            float ga = (x2 - x1) * (y2 - y1);
            float iou = inter / (pa + ga - inter + 1e-6f);
            bxa += 1.0f - iou;
            float ltrb[4] = { dl, dt, dr, db };
#pragma unroll
            for (int k = 0; k < 4; ++k) {
                float tt = fminf(fmaxf(ltrb[k], 0.0f), 15.9999f);
                float lf = floorf(tt);
                int   lb = (int)lf;
                int   rb = lb + 1 > REGMAX ? REGMAX : lb + 1;
                float wl = (float)rb - tt, wr = tt - lf;
                float xl = regp[base_r + (k * BINS + lb) * HW];
                float xr = regp[base_r + (k * BINS + rb) * HW];
                dfa -= (xl - lz[k]) * wl + (xr - lz[k]) * wr;
            }
            int   c   = lab[b * NG + g];
            float xat = clsp[base_c + c * HW];
            cla += fzs - focal0(xat) + focal_t(xat, iou);
        }
    }
    s_ps[s][x] = posi;
    __syncthreads();
    if (s == 0) {
        int pg = s_ps[0][x] | s_ps[1][x] | s_ps[2][x] | s_ps[3][x];
        if (valid && !pg) cla += fzs;   // cls_neg once per point
    }

    // --- block reduction: 4 values over 256 threads ---
    float v0 = bxa, v1 = cla, v2 = dfa, v3 = np;
    for (int off = 32; off > 0; off >>= 1) {
        v0 += __shfl_down(v0, off);
        v1 += __shfl_down(v1, off);
        v2 += __shfl_down(v2, off);
        v3 += __shfl_down(v3, off);
    }
    __shared__ float red[4][4];
    if ((threadIdx.x & 63) == 0) {
        red[s][0] = v0; red[s][1] = v1; red[s][2] = v2; red[s][3] = v3;
    }
    __syncthreads();
    if (threadIdx.x == 0) {
        float s0 = 0, s1 = 0, s2 = 0, s3 = 0;
        for (int w = 0; w < 4; ++w) {
            s0 += red[w][0]; s1 += red[w][1]; s2 += red[w][2]; s3 += red[w][3];
        }
        atomicAdd(&acc[0], s0);
        atomicAdd(&acc[1], s1);
        atomicAdd(&dfln[lvl * NB + b], s2);
        atomicAdd(&npos[lvl * NB + b], s3);
    }
}

// ---------------- pass 4: combine ----------------
__global__ void k_final(const float* __restrict__ acc, const float* __restrict__ npos,
                        const float* __restrict__ dfln, float* __restrict__ out) {
    float tb = acc[0], tc = acc[1], td = 0.0f;
    for (int i = 0; i < 3 * NB; ++i) {
        float n = npos[i];
        if (n > 0.0f) td += dfln[i] / (n * 4.0f);
    }
    out[0] = 7.5f * tb + 1.0f * tc + 1.5f * td;
    out[1] = tb;
    out[2] = tc;
    out[3] = td;
}

extern "C" void kernel_launch(void* const* d_in, const int* in_sizes, int n_in,
                              void* d_out, int out_size, void* d_ws, size_t ws_size,
                              hipStream_t stream) {
    const float* reg0 = (const float*)d_in[0];
    const float* cls0 = (const float*)d_in[1];
    const float* reg1 = (const float*)d_in[2];
    const float* cls1 = (const float*)d_in[3];
    const float* reg2 = (const float*)d_in[4];
    const float* cls2 = (const float*)d_in[5];
    const float* gtb  = (const float*)d_in[6];
    const int*   lab  = (const int*)d_in[7];
    float* out = (float*)d_out;

    char*  ws   = (char*)d_ws;
    float* acc  = (float*)(ws + WS_ACC);
    float* npos = (float*)(ws + WS_NPOS);
    float* dfln = (float*)(ws + WS_DFLN);
    int*   anyp = (int*)(ws + WS_ANYP);
    int*   fb   = (int*)(ws + WS_FB);

    hipMemsetAsync(d_ws, 0, WS_TOTAL, stream);

    k_anypos_f<<<dim3(34, NB), 256, 0, stream>>>(gtb, anyp);
    k_fallback_f<<<dim3(NB, 3), 64, 0, stream>>>(gtb, anyp, fb);
    // L0: 100 blocks/batch, L1: 25, L2: 7  -> 132 x 16, 64 points/block
    k_main_f<<<dim3(132, NB), 256, 0, stream>>>(reg0, cls0, reg1, cls1, reg2, cls2,
                                                gtb, lab, anyp, fb,
                                                acc, npos, dfln);
    k_final<<<1, 1, 0, stream>>>(acc, npos, dfln, out);
}

// Round 4
// 68.702 us; speedup vs baseline: 2.5487x; 1.6425x over previous
//
#include <hip/hip_runtime.h>
#include <math.h>

#define NCLS 80
#define BINS 17
#define REGMAX 16
#define NG 32
#define NB 16
#define KTOP 10
#define RAD 2.5f

// ---------- workspace layout (bytes) ----------
// acc[2]f @0, npos[48]f @32, dfln[48]f @224, anyp[48]i @416, cnt i @608,
// fb[3*16*32*10]i @640
#define WS_ACC   0
#define WS_NPOS  32
#define WS_DFLN  224
#define WS_ANYP  416
#define WS_CNT   608
#define WS_FB    640
#define NBLOCKS  (67 * 16)

// focal_bce with t=0: ce*0.75*p^2   (single exp + single log)
__device__ __forceinline__ float focal0(float x) {
    float e   = __expf(-fabsf(x));
    float inv = 1.0f / (1.0f + e);
    float p   = (x >= 0.0f) ? inv : e * inv;          // sigmoid(x)
    float ce  = fmaxf(x, 0.0f) + __logf(1.0f + e);
    return ce * 0.75f * p * p;
}

__device__ __forceinline__ float focal_t(float x, float t) {
    float e   = __expf(-fabsf(x));
    float inv = 1.0f / (1.0f + e);
    float p   = (x >= 0.0f) ? inv : e * inv;
    float ce  = fmaxf(x, 0.0f) - x * t + __logf(1.0f + e);
    float pt  = p * t + (1.0f - p) * (1.0f - t);
    float at  = 0.25f * t + 0.75f * (1.0f - t);
    float om  = 1.0f - pt;
    return ce * at * om * om;
}

// ---- prep: zero accumulators, exact any_pos via windowed scan, fallback ----
__global__ void k_prep(const float* __restrict__ gtb,
                       float* __restrict__ acc, float* __restrict__ npos,
                       float* __restrict__ dfln, int* __restrict__ anyp,
                       int* __restrict__ cnt, int* __restrict__ fb) {
    int lvl = blockIdx.x;
    int tid = threadIdx.x;               // 512 threads: b = tid>>5, g = tid&31
    int b = tid >> 5, g = tid & 31;
    int W = (lvl == 0) ? 80 : (lvl == 1 ? 40 : 20);
    float inv_s = (lvl == 0) ? 0.125f : (lvl == 1 ? 0.0625f : 0.03125f);
    if (lvl == 0) {
        if (tid < 2)  acc[tid] = 0.0f;
        if (tid < 48) { npos[tid] = 0.0f; dfln[tid] = 0.0f; }
        if (tid == 48) *cnt = 0;
    }
    __shared__ int s_any[NB];
    if (tid < NB) s_any[tid] = 0;
    __syncthreads();

    const float* bb = gtb + (b * NG + g) * 4;
    float x1 = bb[0] * inv_s, y1 = bb[1] * inv_s;
    float x2 = bb[2] * inv_s, y2 = bb[3] * inv_s;
    float gcx = (x1 + x2) * 0.5f, gcy = (y1 + y2) * 0.5f;
    // exact brute scan over a window that provably contains all positives
    int j0 = max((int)floorf(gcx) - 4, 0), j1 = min((int)floorf(gcx) + 4, W - 1);
    int i0 = max((int)floorf(gcy) - 4, 0), i1 = min((int)floorf(gcy) + 4, W - 1);
    bool any = false;
    for (int i = i0; i <= i1; ++i) {
        float cy = (float)i + 0.5f;
        for (int j = j0; j <= j1; ++j) {
            float cx = (float)j + 0.5f;
            bool m = (cx - x1 > 0.0f) && (cy - y1 > 0.0f) &&
                     (x2 - cx > 0.0f) && (y2 - cy > 0.0f) &&
                     (cx >= gcx - RAD) && (cx <= gcx + RAD) &&
                     (cy >= gcy - RAD) && (cy <= gcy + RAD);
            any = any || m;
        }
    }
    if (any) atomicOr(&s_any[b], 1);
    __syncthreads();
    if (g == 0) anyp[lvl * NB + b] = s_any[b];

    // fallback top-10 (essentially never taken)
    if (!s_any[b]) {
        float bd[KTOP]; int bi[KTOP];
        for (int t = 0; t < KTOP; ++t) { bd[t] = 3.0e38f; bi[t] = 0; }
        int HW = W * W;
        for (int p = 0; p < HW; ++p) {
            float cx = (float)(p % W) + 0.5f;
            float cy = (float)(p / W) + 0.5f;
            float dx = cx - gcx, dy = cy - gcy;
            float d = dx * dx + dy * dy;
            if (d < bd[KTOP - 1]) {
                int t = KTOP - 1;
                while (t > 0 && d < bd[t - 1]) { bd[t] = bd[t-1]; bi[t] = bi[t-1]; --t; }
                bd[t] = d; bi[t] = p;
            }
        }
        int* o = fb + ((lvl * NB + b) * NG + g) * KTOP;
        for (int t = 0; t < KTOP; ++t) o[t] = bi[t];
    }
}

// ---- main: 128-point tiles, 4 slice-waves, float2 loads, g-culling ----
__global__ __launch_bounds__(256) void k_main_f(
    const float* __restrict__ reg0, const float* __restrict__ cls0,
    const float* __restrict__ reg1, const float* __restrict__ cls1,
    const float* __restrict__ reg2, const float* __restrict__ cls2,
    const float* __restrict__ gtb,  const int* __restrict__ lab,
    const int* __restrict__ anyp,   const int* __restrict__ fb,
    float* __restrict__ acc, float* __restrict__ npos, float* __restrict__ dfln,
    int* __restrict__ cnt, float* __restrict__ out)
{
    int bx = blockIdx.x;
    int b  = blockIdx.y;
    int lvl, tix, W; const float *regp, *clsp; float inv_s;
    if (bx < 50)      { lvl = 0; tix = bx;      W = 80; regp = reg0; clsp = cls0; inv_s = 0.125f;   }
    else if (bx < 63) { lvl = 1; tix = bx - 50; W = 40; regp = reg1; clsp = cls1; inv_s = 0.0625f;  }
    else              { lvl = 2; tix = bx - 63; W = 20; regp = reg2; clsp = cls2; inv_s = 0.03125f; }
    int HW = W * W;
    int tile = tix * 128;

    int lane = threadIdx.x & 63;
    int s    = threadIdx.x >> 6;
    int q0   = tile + 2 * lane;          // this thread's two points: q0, q0+1
    bool v   = q0 < HW;                  // HW even -> q0+1 also valid when v
    int qc   = v ? q0 : 0;
    int ri0  = qc / W, ci0 = qc - ri0 * W;
    float cx0 = (float)ci0 + 0.5f, cy0 = (float)ri0 + 0.5f;
    int ci1 = ci0 + 1, ri1 = ri0; if (ci1 == W) { ci1 = 0; ri1 = ri0 + 1; }
    float cx1 = (float)ci1 + 0.5f, cy1 = (float)ri1 + 0.5f;

    int base_r = (b * 4 * BINS) * HW + qc;
    int base_c = (b * NCLS) * HW + qc;

    __shared__ float s_dv[4][128], s_lz[4][128], s_fz[4][128];
    __shared__ unsigned char s_ps[4][128];

    // --- phase 1: softmax stats for distribution k = s (both points) ---
    {
        float2 xv[BINS];
#pragma unroll
        for (int t = 0; t < BINS; ++t)
            xv[t] = v ? *(const float2*)(regp + base_r + (s * BINS + t) * HW)
                      : make_float2(0.0f, 0.0f);
        float m0 = xv[0].x, m1 = xv[0].y;
#pragma unroll
        for (int t = 1; t < BINS; ++t) { m0 = fmaxf(m0, xv[t].x); m1 = fmaxf(m1, xv[t].y); }
        float sa = 0.f, ea = 0.f, sb = 0.f, eb = 0.f;
#pragma unroll
        for (int t = 0; t < BINS; ++t) {
            float a = __expf(xv[t].x - m0), c = __expf(xv[t].y - m1);
            sa += a; ea += a * (float)t; sb += c; eb += c * (float)t;
        }
        s_dv[s][2*lane]   = ea / sa;  s_lz[s][2*lane]   = __logf(sa) + m0;
        s_dv[s][2*lane+1] = eb / sb;  s_lz[s][2*lane+1] = __logf(sb) + m1;
    }
    // --- phase 1b: focal0 over classes [s*20, s*20+20) (both points) ---
    {
        float fz0 = 0.f, fz1 = 0.f;
#pragma unroll 4
        for (int t = 0; t < 20; ++t) {
            float2 c2 = v ? *(const float2*)(clsp + base_c + (s * 20 + t) * HW)
                          : make_float2(0.0f, 0.0f);
            fz0 += focal0(c2.x); fz1 += focal0(c2.y);
        }
        s_fz[s][2*lane] = fz0; s_fz[s][2*lane+1] = fz1;
    }
    __syncthreads();

    float dv0[4], lz0v[4], dv1[4], lz1v[4];
#pragma unroll
    for (int k = 0; k < 4; ++k) {
        dv0[k] = s_dv[k][2*lane];   lz0v[k] = s_lz[k][2*lane];
        dv1[k] = s_dv[k][2*lane+1]; lz1v[k] = s_lz[k][2*lane+1];
    }
    float fzs0 = s_fz[0][2*lane]   + s_fz[1][2*lane]   + s_fz[2][2*lane]   + s_fz[3][2*lane];
    float fzs1 = s_fz[0][2*lane+1] + s_fz[1][2*lane+1] + s_fz[2][2*lane+1] + s_fz[3][2*lane+1];

    float px1_0 = cx0 - dv0[0], py1_0 = cy0 - dv0[1];
    float px2_0 = cx0 + dv0[2], py2_0 = cy0 + dv0[3];
    float pa0 = (px2_0 - px1_0) * (py2_0 - py1_0);
    float px1_1 = cx1 - dv1[0], py1_1 = cy1 - dv1[1];
    float px2_1 = cx1 + dv1[2], py2_1 = cy1 + dv1[3];
    float pa1 = (px2_1 - px1_1) * (py2_1 - py1_1);

    bool anyb = anyp[lvl * NB + b] != 0;
    float bxa = 0.f, cla = 0.f, dfa = 0.f, np = 0.f;
    bool posi0 = false, posi1 = false;

#define HEAVY(G, CX, CY, DL, DT, DR, DB, PX1, PY1, PX2, PY2, PA, LZ, FZS, OFF) do { \
    float ix1 = fmaxf(PX1, x1), iy1 = fmaxf(PY1, y1);                    \
    float ix2 = fminf(PX2, x2), iy2 = fminf(PY2, y2);                    \
    float iw = fmaxf(ix2 - ix1, 0.f), ih = fmaxf(iy2 - iy1, 0.f);        \
    float inter = iw * ih;                                               \
    float ga = (x2 - x1) * (y2 - y1);                                    \
    float iou = inter / (PA + ga - inter + 1e-6f);                       \
    bxa += 1.f - iou; np += 1.f;                                         \
    float ltrb[4] = { DL, DT, DR, DB };                                  \
    _Pragma("unroll")                                                    \
    for (int k = 0; k < 4; ++k) {                                        \
        float tt = fminf(fmaxf(ltrb[k], 0.f), 15.9999f);                 \
        float lf = floorf(tt); int lb = (int)lf;                         \
        int rb = lb + 1 > REGMAX ? REGMAX : lb + 1;                      \
        float wl = (float)rb - tt, wr = tt - lf;                         \
        float xl = regp[base_r + OFF + (k * BINS + lb) * HW];            \
        float xr = regp[base_r + OFF + (k * BINS + rb) * HW];            \
        dfa -= (xl - LZ[k]) * wl + (xr - LZ[k]) * wr;                    \
    }                                                                    \
    int c = lab[b * NG + G];                                             \
    float xat = clsp[base_c + OFF + c * HW];                             \
    cla += FZS - focal0(xat) + focal_t(xat, iou);                        \
} while (0)

#define PROC_G(G, GEOM) do {                                             \
    const float* bbp = gtb + (b * NG + (G)) * 4;                         \
    float x1 = bbp[0] * inv_s, y1 = bbp[1] * inv_s;                      \
    float x2 = bbp[2] * inv_s, y2 = bbp[3] * inv_s;                      \
    float dl0 = cx0 - x1, dt0 = cy0 - y1, dr0 = x2 - cx0, db0 = y2 - cy0;\
    float dl1 = cx1 - x1, dt1 = cy1 - y1, dr1 = x2 - cx1, db1 = y2 - cy1;\
    bool m0, m1;                                                         \
    if (GEOM) {                                                          \
        float gx = (x1 + x2) * 0.5f, gy = (y1 + y2) * 0.5f;              \
        m0 = (dl0 > 0.f) && (dt0 > 0.f) && (dr0 > 0.f) && (db0 > 0.f) && \
             (cx0 >= gx - RAD) && (cx0 <= gx + RAD) &&                   \
             (cy0 >= gy - RAD) && (cy0 <= gy + RAD);                     \
        m1 = (dl1 > 0.f) && (dt1 > 0.f) && (dr1 > 0.f) && (db1 > 0.f) && \
             (cx1 >= gx - RAD) && (cx1 <= gx + RAD) &&                   \
             (cy1 >= gy - RAD) && (cy1 <= gy + RAD);                     \
    } else {                                                             \
        const int* fbp = fb + ((lvl * NB + b) * NG + (G)) * KTOP;        \
        m0 = false; m1 = false;                                          \
        _Pragma("unroll")                                                \
        for (int t = 0; t < KTOP; ++t) {                                 \
            int f = fbp[t]; m0 = m0 || (f == q0); m1 = m1 || (f == q0+1);\
        }                                                                \
    }                                                                    \
    m0 = m0 && v; m1 = m1 && v;                                          \
    if (__any(m0 || m1)) {                                               \
        if (m0) HEAVY((G), cx0, cy0, dl0, dt0, dr0, db0,                 \
                      px1_0, py1_0, px2_0, py2_0, pa0, lz0v, fzs0, 0);   \
        if (m1) HEAVY((G), cx1, cy1, dl1, dt1, dr1, db1,                 \
                      px1_1, py1_1, px2_1, py2_1, pa1, lz1v, fzs1, 1);   \
    }                                                                    \
    posi0 = posi0 || m0; posi1 = posi1 || m1;                            \
} while (0)

    if (anyb) {
        // g-culling: row-range overlap test (conservative superset)
        int gg = lane & 31;
        const float* bbg = gtb + (b * NG + gg) * 4;
        float gy1 = bbg[1] * inv_s, gy2 = bbg[3] * inv_s;
        float gcy = (gy1 + gy2) * 0.5f;
        int r0 = tile / W;
        int r1 = min(tile + 127, HW - 1) / W;
        float cyLo = (float)r0 + 0.5f, cyHi = (float)r1 + 0.5f;
        bool act = (cyHi > gy1) && (gy2 > cyLo) &&
                   (cyHi >= gcy - RAD) && (cyLo <= gcy + RAD);
        unsigned long long bm = __ballot(act);
        unsigned m32 = (unsigned)(bm | (bm >> 32));
        int ord = 0;
        while (m32) {
            int g = __builtin_ctz(m32); m32 &= m32 - 1;
            if ((ord++ & 3) == s) PROC_G(g, true);
        }
    } else {
        for (int t = 0; t < 8; ++t) { int g = s * 8 + t; PROC_G(g, false); }
    }

    s_ps[s][2*lane] = posi0; s_ps[s][2*lane+1] = posi1;
    __syncthreads();
    if (s == 0) {
        int pg0 = s_ps[0][2*lane] | s_ps[1][2*lane] | s_ps[2][2*lane] | s_ps[3][2*lane];
        int pg1 = s_ps[0][2*lane+1] | s_ps[1][2*lane+1] | s_ps[2][2*lane+1] | s_ps[3][2*lane+1];
        if (v && !pg0) cla += fzs0;
        if (v && !pg1) cla += fzs1;
    }

    // --- block reduction: 4 values over 256 threads ---
    float v0 = bxa, v1 = cla, v2 = dfa, v3 = np;
    for (int off = 32; off > 0; off >>= 1) {
        v0 += __shfl_down(v0, off);
        v1 += __shfl_down(v1, off);
        v2 += __shfl_down(v2, off);
        v3 += __shfl_down(v3, off);
    }
    __shared__ float red[4][4];
    if (lane == 0) { red[s][0] = v0; red[s][1] = v1; red[s][2] = v2; red[s][3] = v3; }
    __syncthreads();
    if (threadIdx.x == 0) {
        float t0 = 0, t1 = 0, t2 = 0, t3 = 0;
        for (int w = 0; w < 4; ++w) {
            t0 += red[w][0]; t1 += red[w][1]; t2 += red[w][2]; t3 += red[w][3];
        }
        atomicAdd(&acc[0], t0);
        atomicAdd(&acc[1], t1);
        atomicAdd(&dfln[lvl * NB + b], t2);
        atomicAdd(&npos[lvl * NB + b], t3);
    }

    // --- last block finalizes the output ---
    __shared__ int s_tick;
    if (threadIdx.x == 0) {
        __threadfence();
        s_tick = atomicAdd(cnt, 1);
    }
    __syncthreads();
    if (s_tick == NBLOCKS - 1 && threadIdx.x < 64) {
        float vs = 0.f;
        if (lane < 48) {
            float n = atomicAdd(&npos[lane], 0.0f);   // coherent read
            float d = atomicAdd(&dfln[lane], 0.0f);
            if (n > 0.f) vs = d / (n * 4.0f);
        }
        for (int off = 32; off > 0; off >>= 1) vs += __shfl_down(vs, off);
        if (lane == 0) {
            float tbv = atomicAdd(&acc[0], 0.0f);
            float tcv = atomicAdd(&acc[1], 0.0f);
            out[0] = 7.5f * tbv + tcv + 1.5f * vs;
            out[1] = tbv; out[2] = tcv; out[3] = vs;
        }
    }
}

extern "C" void kernel_launch(void* const* d_in, const int* in_sizes, int n_in,
                              void* d_out, int out_size, void* d_ws, size_t ws_size,
                              hipStream_t stream) {
    const float* reg0 = (const float*)d_in[0];
    const float* cls0 = (const float*)d_in[1];
    const float* reg1 = (const float*)d_in[2];
    const float* cls1 = (const float*)d_in[3];
    const float* reg2 = (const float*)d_in[4];
    const float* cls2 = (const float*)d_in[5];
    const float* gtb  = (const float*)d_in[6];
    const int*   lab  = (const int*)d_in[7];
    float* out = (float*)d_out;

    char*  ws   = (char*)d_ws;
    float* acc  = (float*)(ws + WS_ACC);
    float* npos = (float*)(ws + WS_NPOS);
    float* dfln = (float*)(ws + WS_DFLN);
    int*   anyp = (int*)(ws + WS_ANYP);
    int*   cnt  = (int*)(ws + WS_CNT);
    int*   fb   = (int*)(ws + WS_FB);

    k_prep<<<3, 512, 0, stream>>>(gtb, acc, npos, dfln, anyp, cnt, fb);
    // L0: 50 tiles/batch, L1: 13, L2: 4  -> 67 x 16 blocks, 128 points/tile
    k_main_f<<<dim3(67, NB), 256, 0, stream>>>(reg0, cls0, reg1, cls1, reg2, cls2,
                                               gtb, lab, anyp, fb,
                                               acc, npos, dfln, cnt, out);
}